// Round 1
// baseline (1735.520 us; speedup 1.0000x reference)
//
#include <hip/hip_runtime.h>
#include <hip/hip_bf16.h>
#include <cstdint>

// Problem: B=16384, L=5, D=1024.  Rows M = B*L = 81920.
// scores = x^T (Wq^T Wk) x  ->  Gt[n,k] = sum_e Wq[e,k]*Wk[e,n]; u = x@G; s = rowdot(u,x)/32.
//
// Pipeline:
//   k_cvt_bf16:  x -> xb (bf16, ws), Wv/W1/W2 -> bf16 (ws)
//   k_gt:        Gt = bilinear matrix (bf16, ws)
//   k_gemm<0>:   u = xb @ Gt^T(BT)      -> d_out[0:] as bf16
//   k_gemm<0>:   v = xb @ Wv^T          -> d_out[+84M elems] as bf16
//   k_attn_ln:   scores->softmax->attn, y = LN(attn+x) -> yb (in-place over xb)
//   k_gemm<1>:   h = GELU(yb @ W1^T + b1) -> hb (ws)
//   k_gemm<2>:   z = hb @ W2^T + b2 + yb  -> d_out (fp32, overwrites u/v)
//   k_ln_final:  d_out = LN(z)*ff_g + ff_b   (in-place)
//
// ws requirement: 2*83886080 (xb) + 2*83886080 (hb) + 4*2MB weights ~= 344 MB.

typedef float f32x4 __attribute__((ext_vector_type(4)));
typedef __bf16 bf16x8 __attribute__((ext_vector_type(8)));

#define NROWS 81920L
#define DD 1024

__device__ __forceinline__ unsigned short f2bf(float f) {
  union { float f; unsigned u; } c; c.f = f;
  unsigned u = c.u;
  return (unsigned short)((u + 0x7FFFu + ((u >> 16) & 1u)) >> 16);  // RNE
}
__device__ __forceinline__ float bf2f(unsigned short b) {
  union { unsigned u; float f; } c; c.u = ((unsigned)b) << 16;
  return c.f;
}
__device__ __forceinline__ void unpack8(uint4 v, float* o) {
  o[0] = bf2f((unsigned short)(v.x & 0xffffu)); o[1] = bf2f((unsigned short)(v.x >> 16));
  o[2] = bf2f((unsigned short)(v.y & 0xffffu)); o[3] = bf2f((unsigned short)(v.y >> 16));
  o[4] = bf2f((unsigned short)(v.z & 0xffffu)); o[5] = bf2f((unsigned short)(v.z >> 16));
  o[6] = bf2f((unsigned short)(v.w & 0xffffu)); o[7] = bf2f((unsigned short)(v.w >> 16));
}

__device__ __forceinline__ void gload_lds16(const void* g, void* l) {
  __builtin_amdgcn_global_load_lds(
      (const __attribute__((address_space(1))) unsigned int*)g,
      (__attribute__((address_space(3))) unsigned int*)l, 16, 0, 0);
}

// ---------------- fp32 -> bf16 conversion (vectorized, grid-stride) ----------------
__global__ void __launch_bounds__(256) k_cvt_bf16(const float* __restrict__ in,
                                                  unsigned short* __restrict__ out, long n) {
  long i = ((long)blockIdx.x * blockDim.x + threadIdx.x) * 8;
  long stride = (long)gridDim.x * blockDim.x * 8;
  for (; i < n; i += stride) {
    f32x4 a = *(const f32x4*)(in + i);
    f32x4 b = *(const f32x4*)(in + i + 4);
    uint4 o;
    o.x = (unsigned)f2bf(a[0]) | ((unsigned)f2bf(a[1]) << 16);
    o.y = (unsigned)f2bf(a[2]) | ((unsigned)f2bf(a[3]) << 16);
    o.z = (unsigned)f2bf(b[0]) | ((unsigned)f2bf(b[1]) << 16);
    o.w = (unsigned)f2bf(b[2]) | ((unsigned)f2bf(b[3]) << 16);
    *(uint4*)(out + i) = o;
  }
}

// ---------------- Gt[n,k] = sum_e Wk[e,n] * Wq[e,k]  (1024^3 fp32, tiled) ----------------
__global__ void __launch_bounds__(256) k_gt(const float* __restrict__ Wq,
                                            const float* __restrict__ Wk,
                                            unsigned short* __restrict__ Gt) {
  __shared__ float sk[16][16];   // [e][n]
  __shared__ float sq[16][64];   // [e][k]
  const int tx = threadIdx.x, ty = threadIdx.y;
  const int n0 = blockIdx.y * 16;
  const int k0 = blockIdx.x * 64;
  float acc[4] = {0.f, 0.f, 0.f, 0.f};
  for (int e0 = 0; e0 < 1024; e0 += 16) {
    sk[ty][tx] = Wk[(long)(e0 + ty) * DD + n0 + tx];
    *(f32x4*)&sq[ty][tx * 4] = *(const f32x4*)&Wq[(long)(e0 + ty) * DD + k0 + tx * 4];
    __syncthreads();
#pragma unroll
    for (int ee = 0; ee < 16; ++ee) {
      float kv = sk[ee][ty];
      f32x4 qv = *(const f32x4*)&sq[ee][tx * 4];
      acc[0] += kv * qv[0]; acc[1] += kv * qv[1];
      acc[2] += kv * qv[2]; acc[3] += kv * qv[3];
    }
    __syncthreads();
  }
  uint2 o;
  o.x = (unsigned)f2bf(acc[0]) | ((unsigned)f2bf(acc[1]) << 16);
  o.y = (unsigned)f2bf(acc[2]) | ((unsigned)f2bf(acc[3]) << 16);
  *(uint2*)&Gt[(long)(n0 + ty) * DD + k0 + tx * 4] = o;
}

// ---------------- BT-GEMM: C[m,n] = sum_k A[m,k]*B[n,k], bf16 MFMA, 128x128x64 ----------------
// EPI 0: store bf16.  EPI 1: GELU(acc+bias) -> bf16.  EPI 2: acc+bias+resid(bf16) -> fp32.
template <int EPI>
__global__ void __launch_bounds__(256) k_gemm_bt(
    const unsigned short* __restrict__ A,   // [M,1024] bf16
    const unsigned short* __restrict__ B,   // [1024,1024] bf16
    unsigned short* __restrict__ outb,
    float* __restrict__ outf,
    const float* __restrict__ bias,
    const unsigned short* __restrict__ resid) {
  __shared__ __align__(16) unsigned short As[128 * 64];
  __shared__ __align__(16) unsigned short Bs[128 * 64];
  const int tid = threadIdx.x;
  const int lane = tid & 63;
  const int w = tid >> 6;
  const int wm = w >> 1, wn = w & 1;
  const long m0 = (long)blockIdx.y * 128;
  const int n0 = blockIdx.x * 128;

  f32x4 acc[4][4];
#pragma unroll
  for (int i = 0; i < 4; ++i)
#pragma unroll
    for (int j = 0; j < 4; ++j) acc[i][j] = f32x4{0.f, 0.f, 0.f, 0.f};

  const char* Abase = (const char*)(A + m0 * DD);
  const char* Bbase = (const char*)(B + (long)n0 * DD);
  char* AsB = (char*)As;
  char* BsB = (char*)Bs;

  const int frow = lane & 15;
  const int fk = (lane >> 4) * 8;
  const int aoff0 = (wm * 64 + frow) * 128 + fk * 2;  // bytes
  const int boff0 = (wn * 64 + frow) * 128 + fk * 2;

  for (int kt = 0; kt < 16; ++kt) {
    const int k0b = kt * 128;  // byte offset of this K-slice within a row
#pragma unroll
    for (int c = 0; c < 4; ++c) {
      int off = c * 4096 + tid * 16;
      int row = off >> 7;
      int kb = off & 127;
      gload_lds16(Abase + (long)row * 2048 + k0b + kb, AsB + off);
    }
#pragma unroll
    for (int c = 0; c < 4; ++c) {
      int off = c * 4096 + tid * 16;
      int row = off >> 7;
      int kb = off & 127;
      gload_lds16(Bbase + (long)row * 2048 + k0b + kb, BsB + off);
    }
    __syncthreads();  // drains vmcnt for global_load_lds

    bf16x8 fa[2][4], fb[2][4];
#pragma unroll
    for (int kk = 0; kk < 2; ++kk)
#pragma unroll
      for (int i = 0; i < 4; ++i) {
        fa[kk][i] = *(const bf16x8*)(AsB + aoff0 + i * 2048 + kk * 64);
        fb[kk][i] = *(const bf16x8*)(BsB + boff0 + i * 2048 + kk * 64);
      }
#pragma unroll
    for (int kk = 0; kk < 2; ++kk)
#pragma unroll
      for (int i = 0; i < 4; ++i)
#pragma unroll
        for (int j = 0; j < 4; ++j)
          acc[i][j] = __builtin_amdgcn_mfma_f32_16x16x32_bf16(fa[kk][i], fb[kk][j], acc[i][j], 0, 0, 0);
    __syncthreads();
  }

  // epilogue: C row = m0 + wm*64 + i*16 + (lane>>4)*4 + t ; col = n0 + wn*64 + j*16 + (lane&15)
  const int crow0 = wm * 64 + (lane >> 4) * 4;
  const int ccol0 = n0 + wn * 64 + (lane & 15);
#pragma unroll
  for (int i = 0; i < 4; ++i) {
#pragma unroll
    for (int j = 0; j < 4; ++j) {
      const int ccol = ccol0 + j * 16;
      float bv = 0.f;
      if constexpr (EPI != 0) bv = bias[ccol];
#pragma unroll
      for (int t = 0; t < 4; ++t) {
        const long r = m0 + crow0 + i * 16 + t;
        float v = acc[i][j][t];
        if constexpr (EPI == 0) {
          outb[r * DD + ccol] = f2bf(v);
        } else if constexpr (EPI == 1) {
          v += bv;
          float g = 0.5f * v * (1.0f + erff(v * 0.70710678118654752f));
          outb[r * DD + ccol] = f2bf(g);
        } else {
          v += bv + bf2f(resid[r * DD + ccol]);
          outf[r * DD + ccol] = v;
        }
      }
    }
  }
}

// ---------------- per-batch: scores -> softmax -> attn -> LN -> yb (in-place over xb) ----------------
__global__ void __launch_bounds__(64) k_attn_ln(
    const unsigned short* __restrict__ xb, const unsigned short* __restrict__ ub,
    const unsigned short* __restrict__ vb, unsigned short* __restrict__ yb,
    const int* __restrict__ mask, const float* __restrict__ att_g,
    const float* __restrict__ att_b) {
  const int b = blockIdx.x;
  const int lane = threadIdx.x;
  const long base = (long)b * (5 * DD) + lane * 16;

  float xr[5][16];
  float sc[5];
#pragma unroll
  for (int l = 0; l < 5; ++l) {
    const unsigned short* xp = xb + base + l * DD;
    const unsigned short* up = ub + base + l * DD;
    uint4 x0 = *(const uint4*)xp, x1 = *(const uint4*)(xp + 8);
    uint4 u0 = *(const uint4*)up, u1 = *(const uint4*)(up + 8);
    unpack8(x0, xr[l]); unpack8(x1, xr[l] + 8);
    float uu[16];
    unpack8(u0, uu); unpack8(u1, uu + 8);
    float d = 0.f;
#pragma unroll
    for (int c = 0; c < 16; ++c) d += xr[l][c] * uu[c];
#pragma unroll
    for (int off = 32; off; off >>= 1) d += __shfl_xor(d, off);
    sc[l] = d * 0.03125f;  // / sqrt(1024)
  }
  bool keep[5];
  float m = -1e30f;
#pragma unroll
  for (int l = 0; l < 5; ++l) {
    keep[l] = (mask[l] != 0);
    if (keep[l]) m = fmaxf(m, sc[l]);
  }
  float p[5], s = 0.f;
#pragma unroll
  for (int l = 0; l < 5; ++l) {
    p[l] = keep[l] ? __expf(sc[l] - m) : 0.f;
    s += p[l];
  }
  const float inv = 1.f / s;

  float gg[16], bb[16];
  {
    const float* gp = att_g + lane * 16;
    const float* bp = att_b + lane * 16;
#pragma unroll
    for (int q = 0; q < 4; ++q) {
      f32x4 gv = *(const f32x4*)(gp + q * 4);
      f32x4 bv = *(const f32x4*)(bp + q * 4);
#pragma unroll
      for (int c = 0; c < 4; ++c) { gg[q * 4 + c] = gv[c]; bb[q * 4 + c] = bv[c]; }
    }
  }

#pragma unroll
  for (int l = 0; l < 5; ++l) {
    const unsigned short* vp = vb + base + l * DD;
    float vv[16];
    unpack8(*(const uint4*)vp, vv);
    unpack8(*(const uint4*)(vp + 8), vv + 8);
    const float pl = p[l] * inv;
    float t[16], sm = 0.f, sq = 0.f;
#pragma unroll
    for (int c = 0; c < 16; ++c) {
      t[c] = pl * vv[c] + xr[l][c];
      sm += t[c];
      sq += t[c] * t[c];
    }
#pragma unroll
    for (int off = 32; off; off >>= 1) {
      sm += __shfl_xor(sm, off);
      sq += __shfl_xor(sq, off);
    }
    const float mu = sm * (1.f / 1024.f);
    const float var = sq * (1.f / 1024.f) - mu * mu;
    const float rs = rsqrtf(var + 1e-5f);
    unsigned short r[16];
#pragma unroll
    for (int c = 0; c < 16; ++c) r[c] = f2bf((t[c] - mu) * rs * gg[c] + bb[c]);
    uint4 o0, o1;
    o0.x = (unsigned)r[0] | ((unsigned)r[1] << 16);  o0.y = (unsigned)r[2] | ((unsigned)r[3] << 16);
    o0.z = (unsigned)r[4] | ((unsigned)r[5] << 16);  o0.w = (unsigned)r[6] | ((unsigned)r[7] << 16);
    o1.x = (unsigned)r[8] | ((unsigned)r[9] << 16);  o1.y = (unsigned)r[10] | ((unsigned)r[11] << 16);
    o1.z = (unsigned)r[12] | ((unsigned)r[13] << 16); o1.w = (unsigned)r[14] | ((unsigned)r[15] << 16);
    unsigned short* yp = yb + base + l * DD;
    *(uint4*)yp = o0;
    *(uint4*)(yp + 8) = o1;
  }
}

// ---------------- final LN in-place on d_out (fp32), wave-per-row ----------------
__global__ void __launch_bounds__(256) k_ln_final(float* __restrict__ z,
                                                  const float* __restrict__ g,
                                                  const float* __restrict__ bb) {
  const int lane = threadIdx.x & 63;
  const long row = (long)blockIdx.x * 4 + (threadIdx.x >> 6);
  float* p = z + row * DD + lane * 16;
  f32x4 v[4];
  float sm = 0.f, sq = 0.f;
#pragma unroll
  for (int q = 0; q < 4; ++q) {
    v[q] = *(const f32x4*)(p + q * 4);
#pragma unroll
    for (int c = 0; c < 4; ++c) { sm += v[q][c]; sq += v[q][c] * v[q][c]; }
  }
#pragma unroll
  for (int off = 32; off; off >>= 1) {
    sm += __shfl_xor(sm, off);
    sq += __shfl_xor(sq, off);
  }
  const float mu = sm * (1.f / 1024.f);
  const float var = sq * (1.f / 1024.f) - mu * mu;
  const float rs = rsqrtf(var + 1e-5f);
  const float* gp = g + lane * 16;
  const float* bp = bb + lane * 16;
#pragma unroll
  for (int q = 0; q < 4; ++q) {
    f32x4 gv = *(const f32x4*)(gp + q * 4);
    f32x4 bv = *(const f32x4*)(bp + q * 4);
#pragma unroll
    for (int c = 0; c < 4; ++c) v[q][c] = (v[q][c] - mu) * rs * gv[c] + bv[c];
    *(f32x4*)(p + q * 4) = v[q];
  }
}

extern "C" void kernel_launch(void* const* d_in, const int* in_sizes, int n_in,
                              void* d_out, int out_size, void* d_ws, size_t ws_size,
                              hipStream_t stream) {
  const float* x     = (const float*)d_in[0];
  const int*   mask  = (const int*)d_in[1];
  const float* Wq    = (const float*)d_in[2];
  const float* Wk    = (const float*)d_in[3];
  const float* Wv    = (const float*)d_in[4];
  const float* W1    = (const float*)d_in[5];
  const float* b1    = (const float*)d_in[6];
  const float* W2    = (const float*)d_in[7];
  const float* b2    = (const float*)d_in[8];
  const float* att_g = (const float*)d_in[9];
  const float* att_b = (const float*)d_in[10];
  const float* ff_g  = (const float*)d_in[11];
  const float* ff_b  = (const float*)d_in[12];

  const long NE = NROWS * DD;  // 83,886,080 elements
  unsigned short* xb  = (unsigned short*)d_ws;       // bf16 x, becomes yb after k_attn_ln
  unsigned short* hb  = xb + NE;                     // GELU output
  unsigned short* Gtb = hb + NE;
  unsigned short* Wvb = Gtb + (long)DD * DD;
  unsigned short* W1b = Wvb + (long)DD * DD;
  unsigned short* W2b = W1b + (long)DD * DD;

  unsigned short* ub = (unsigned short*)d_out;       // u in d_out[0 .. 168MB)
  unsigned short* vb = ub + NE;                      // v in d_out[168 .. 336MB)
  unsigned short* yb = xb;
  float* outf = (float*)d_out;

  k_cvt_bf16<<<2048, 256, 0, stream>>>(x, xb, NE);
  k_cvt_bf16<<<512, 256, 0, stream>>>(Wv, Wvb, (long)DD * DD);
  k_cvt_bf16<<<512, 256, 0, stream>>>(W1, W1b, (long)DD * DD);
  k_cvt_bf16<<<512, 256, 0, stream>>>(W2, W2b, (long)DD * DD);
  k_gt<<<dim3(16, 64), dim3(16, 16), 0, stream>>>(Wq, Wk, Gtb);

  dim3 ggrid(8, 640);  // (n-tiles, m-tiles)
  k_gemm_bt<0><<<ggrid, 256, 0, stream>>>(xb, Gtb, ub, nullptr, nullptr, nullptr);
  k_gemm_bt<0><<<ggrid, 256, 0, stream>>>(xb, Wvb, vb, nullptr, nullptr, nullptr);
  k_attn_ln<<<16384, 64, 0, stream>>>(xb, ub, vb, yb, mask, att_g, att_b);
  k_gemm_bt<1><<<ggrid, 256, 0, stream>>>(yb, W1b, hb, nullptr, b1, nullptr);
  k_gemm_bt<2><<<ggrid, 256, 0, stream>>>(hb, W2b, nullptr, outf, b2, yb);
  k_ln_final<<<20480, 256, 0, stream>>>(outf, ff_g, ff_b);
}

// Round 2
// 1349.745 us; speedup vs baseline: 1.2858x; 1.2858x over previous
//
#include <hip/hip_runtime.h>
#include <hip/hip_bf16.h>
#include <cstdint>

// B=16384, L=5, D=1024.  M = 81920 rows.
// scores = x^T (Wq^T Wk) x  ->  Gt[n,k]; u = x@Gt^T; s = rowdot(u,x)/32.
// Pipeline:
//   k_cvt_bf16: x->xb ; Wv->Bcat[1024:2048] ; W1->W1b ; W2->W2b
//   k_gt:       Gt -> Bcat[0:1024]
//   k_gemm256<0>: [u|v] = xb @ Bcat^T  -> d_out as bf16 [M][2048] (u cols 0-1023, v 1024-2047)
//   k_attn_ln:  scores->softmax->attn, y = LN(attn+x) -> xb in place
//   k_gemm256<1>: h = GELU(y @ W1^T + b1) -> hb
//   k_gemm256<2>: z = h @ W2^T + b2 + y   -> d_out fp32
//   k_ln_final: d_out = LN(z)*ff_g+ff_b in place
//
// GEMM: 256x256 tile, BK=32, ring of 4 LDS slots (128 KiB), depth-3 prefetch,
// counted vmcnt(12), raw s_barrier, XOR-swizzled LDS (pre-swizzled global src,
// linear global_load_lds dest), setprio around MFMA, bijective XCD chunking.

typedef float f32x4 __attribute__((ext_vector_type(4)));
typedef __bf16 bf16x8 __attribute__((ext_vector_type(8)));

#define DD 1024
#define NROWS 81920L

__device__ __forceinline__ unsigned short f2bf(float f) {
  union { float f; unsigned u; } c; c.f = f;
  unsigned u = c.u;
  return (unsigned short)((u + 0x7FFFu + ((u >> 16) & 1u)) >> 16);  // RNE
}
__device__ __forceinline__ float bf2f(unsigned short b) {
  union { unsigned u; float f; } c; c.u = ((unsigned)b) << 16;
  return c.f;
}
__device__ __forceinline__ void unpack8(uint4 v, float* o) {
  o[0] = bf2f((unsigned short)(v.x & 0xffffu)); o[1] = bf2f((unsigned short)(v.x >> 16));
  o[2] = bf2f((unsigned short)(v.y & 0xffffu)); o[3] = bf2f((unsigned short)(v.y >> 16));
  o[4] = bf2f((unsigned short)(v.z & 0xffffu)); o[5] = bf2f((unsigned short)(v.z >> 16));
  o[6] = bf2f((unsigned short)(v.w & 0xffffu)); o[7] = bf2f((unsigned short)(v.w >> 16));
}
__device__ __forceinline__ void gload_lds16(const void* g, void* l) {
  __builtin_amdgcn_global_load_lds(
      (const __attribute__((address_space(1))) unsigned int*)g,
      (__attribute__((address_space(3))) unsigned int*)l, 16, 0, 0);
}

// ---------------- fp32 -> bf16 ----------------
__global__ void __launch_bounds__(256) k_cvt_bf16(const float* __restrict__ in,
                                                  unsigned short* __restrict__ out, long n) {
  long i = ((long)blockIdx.x * blockDim.x + threadIdx.x) * 8;
  long stride = (long)gridDim.x * blockDim.x * 8;
  for (; i < n; i += stride) {
    f32x4 a = *(const f32x4*)(in + i);
    f32x4 b = *(const f32x4*)(in + i + 4);
    uint4 o;
    o.x = (unsigned)f2bf(a[0]) | ((unsigned)f2bf(a[1]) << 16);
    o.y = (unsigned)f2bf(a[2]) | ((unsigned)f2bf(a[3]) << 16);
    o.z = (unsigned)f2bf(b[0]) | ((unsigned)f2bf(b[1]) << 16);
    o.w = (unsigned)f2bf(b[2]) | ((unsigned)f2bf(b[3]) << 16);
    *(uint4*)(out + i) = o;
  }
}

// ---------------- Gt[n,k] = sum_e Wk[e,n] * Wq[e,k] ----------------
__global__ void __launch_bounds__(256) k_gt(const float* __restrict__ Wq,
                                            const float* __restrict__ Wk,
                                            unsigned short* __restrict__ Gt) {
  __shared__ float sk[16][16];
  __shared__ float sq[16][64];
  const int tx = threadIdx.x, ty = threadIdx.y;
  const int n0 = blockIdx.y * 16;
  const int k0 = blockIdx.x * 64;
  float acc[4] = {0.f, 0.f, 0.f, 0.f};
  for (int e0 = 0; e0 < 1024; e0 += 16) {
    sk[ty][tx] = Wk[(long)(e0 + ty) * DD + n0 + tx];
    *(f32x4*)&sq[ty][tx * 4] = *(const f32x4*)&Wq[(long)(e0 + ty) * DD + k0 + tx * 4];
    __syncthreads();
#pragma unroll
    for (int ee = 0; ee < 16; ++ee) {
      float kv = sk[ee][ty];
      f32x4 qv = *(const f32x4*)&sq[ee][tx * 4];
      acc[0] += kv * qv[0]; acc[1] += kv * qv[1];
      acc[2] += kv * qv[2]; acc[3] += kv * qv[3];
    }
    __syncthreads();
  }
  uint2 o;
  o.x = (unsigned)f2bf(acc[0]) | ((unsigned)f2bf(acc[1]) << 16);
  o.y = (unsigned)f2bf(acc[2]) | ((unsigned)f2bf(acc[3]) << 16);
  *(uint2*)&Gt[(long)(n0 + ty) * DD + k0 + tx * 4] = o;
}

// ---------------- 256x256 BT-GEMM, BK=32, ring-4 pipeline ----------------
// C[m,n] = sum_k A[m,k]*B[n,k].  K=1024 fixed (32 K-tiles).
// EPI 0: bf16 out.  EPI 1: GELU(acc+bias) bf16.  EPI 2: acc+bias+resid -> fp32.
#define VMBAR(N)                                             \
  do {                                                       \
    asm volatile("s_waitcnt vmcnt(" #N ")" ::: "memory");    \
    __builtin_amdgcn_s_barrier();                            \
    asm volatile("" ::: "memory");                           \
  } while (0)

template <int EPI>
__global__ void __launch_bounds__(512, 2) k_gemm256(
    const unsigned short* __restrict__ A,   // [M,1024] bf16
    const unsigned short* __restrict__ B,   // [N,1024] bf16 (BT layout)
    unsigned short* __restrict__ outb,
    float* __restrict__ outf,
    const float* __restrict__ bias,
    const unsigned short* __restrict__ resid,
    const int ntl2,                          // log2(n-tiles)
    const int cst) {                         // C col-stride (elems)
  __shared__ __align__(16) char ldsB[131072];  // 4 slots x (A 16K + B 16K)
  const int tid = threadIdx.x;
  const int lane = tid & 63;
  const int wid = tid >> 6;
  const int wm = wid >> 2, wn = wid & 3;

  // bijective XCD chunking; logical id is m-major so the n-blocks sharing an
  // A-strip are contiguous on one XCD (A L2-reuse; B is small and L2-resident)
  const int nwg = gridDim.x;
  const int cpx = nwg >> 3;
  const int d = blockIdx.x;
  const int l = (d & 7) * cpx + (d >> 3);
  const int mt = l >> ntl2;
  const int nt = l & ((1 << ntl2) - 1);
  const long m0 = (long)mt * 256;
  const int n0 = nt * 256;

  // ---- staging addressing (linear LDS dest, pre-swizzled global source) ----
  // slot layout: row-major [256 rows][64 B]; swizzle: col granule ^= (row>>1)&3
  const int r0off = tid * 16;
  const int r1off = 8192 + tid * 16;
  const int rw0 = r0off >> 6, rw1 = r1off >> 6;
  const int oc0 = (r0off & 63) ^ (((rw0 >> 1) & 3) << 4);
  const int oc1 = (r1off & 63) ^ (((rw1 >> 1) & 3) << 4);
  const char* sA0 = (const char*)A + (m0 + rw0) * 2048 + oc0;
  const char* sA1 = (const char*)A + (m0 + rw1) * 2048 + oc1;
  const char* sB0 = (const char*)B + (long)(n0 + rw0) * 2048 + oc0;
  const char* sB1 = (const char*)B + (long)(n0 + rw1) * 2048 + oc1;

  // ---- fragment read offsets (swizzled) ----
  const int la = lane & 15, lg = lane >> 4;
  const int cb = ((lg ^ ((la >> 1) & 3)) << 4);
  int aoff[8], boff[4];
#pragma unroll
  for (int mi = 0; mi < 8; ++mi) aoff[mi] = (wm * 128 + mi * 16 + la) * 64 + cb;
#pragma unroll
  for (int nj = 0; nj < 4; ++nj) boff[nj] = (wn * 64 + nj * 16 + la) * 64 + cb;

  f32x4 acc[8][4];
#pragma unroll
  for (int mi = 0; mi < 8; ++mi)
#pragma unroll
    for (int nj = 0; nj < 4; ++nj) acc[mi][nj] = f32x4{0.f, 0.f, 0.f, 0.f};

  auto stage = [&](int kt) {
    char* base = ldsB + ((kt & 3) << 15);
    const long ko = (long)kt << 6;
    gload_lds16(sA0 + ko, base + r0off);
    gload_lds16(sA1 + ko, base + r1off);
    gload_lds16(sB0 + ko, base + 16384 + r0off);
    gload_lds16(sB1 + ko, base + 16384 + r1off);
  };

  auto body = [&](int kt) {
    const char* bA = ldsB + ((kt & 3) << 15);
    const char* bB = bA + 16384;
    bf16x8 fb[4];
#pragma unroll
    for (int nj = 0; nj < 4; ++nj) fb[nj] = *(const bf16x8*)(bB + boff[nj]);
    __builtin_amdgcn_s_setprio(1);
#pragma unroll
    for (int mi = 0; mi < 8; ++mi) {
      bf16x8 a = *(const bf16x8*)(bA + aoff[mi]);
#pragma unroll
      for (int nj = 0; nj < 4; ++nj)
        acc[mi][nj] = __builtin_amdgcn_mfma_f32_16x16x32_bf16(a, fb[nj], acc[mi][nj], 0, 0, 0);
    }
    __builtin_amdgcn_s_setprio(0);
    __builtin_amdgcn_s_barrier();   // readers done before anyone stages over this slot
    asm volatile("" ::: "memory");
  };

  stage(0); stage(1); stage(2);
  for (int kt = 0; kt < 29; ++kt) {
    stage(kt + 3);
    VMBAR(12);   // K-tile kt landed (3 tiles = 12 loads may stay in flight)
    body(kt);
  }
  VMBAR(8);  body(29);
  VMBAR(4);  body(30);
  VMBAR(0);  body(31);

  // ---- epilogue ----
  const long rbase = m0 + wm * 128 + (lane >> 4) * 4;
  const int cbase = n0 + wn * 64 + la;
#pragma unroll
  for (int mi = 0; mi < 8; ++mi) {
#pragma unroll
    for (int nj = 0; nj < 4; ++nj) {
      const int col = cbase + nj * 16;
      float bv = 0.f;
      if constexpr (EPI != 0) bv = bias[col];
#pragma unroll
      for (int t = 0; t < 4; ++t) {
        const long r = rbase + mi * 16 + t;
        float v = acc[mi][nj][t];
        if constexpr (EPI == 0) {
          outb[r * (long)cst + col] = f2bf(v);
        } else if constexpr (EPI == 1) {
          v += bv;
          v = 0.5f * v * (1.0f + erff(v * 0.70710678118654752f));
          outb[r * (long)cst + col] = f2bf(v);
        } else {
          v += bv + bf2f(resid[r * (long)cst + col]);
          outf[r * (long)cst + col] = v;
        }
      }
    }
  }
}

// ---------------- attn + LN (uv interleaved [M][2048]) ----------------
__global__ void __launch_bounds__(256) k_attn_ln(
    const unsigned short* __restrict__ xb, const unsigned short* __restrict__ uv,
    unsigned short* __restrict__ yb, const int* __restrict__ mask,
    const float* __restrict__ att_g, const float* __restrict__ att_b) {
  const int b = blockIdx.x * 4 + (threadIdx.x >> 6);
  const int lane = threadIdx.x & 63;
  const long xbase = (long)b * 5120 + lane * 16;
  const long ubase = (long)b * 10240 + lane * 16;

  float xr[5][16];
  float sc[5];
#pragma unroll
  for (int l = 0; l < 5; ++l) {
    const unsigned short* xp = xb + xbase + l * 1024;
    const unsigned short* up = uv + ubase + l * 2048;
    unpack8(*(const uint4*)xp, xr[l]); unpack8(*(const uint4*)(xp + 8), xr[l] + 8);
    float uu[16];
    unpack8(*(const uint4*)up, uu); unpack8(*(const uint4*)(up + 8), uu + 8);
    float d = 0.f;
#pragma unroll
    for (int c = 0; c < 16; ++c) d += xr[l][c] * uu[c];
#pragma unroll
    for (int off = 32; off; off >>= 1) d += __shfl_xor(d, off);
    sc[l] = d * 0.03125f;
  }
  bool keep[5];
  float m = -1e30f;
#pragma unroll
  for (int l = 0; l < 5; ++l) {
    keep[l] = (mask[l] != 0);
    if (keep[l]) m = fmaxf(m, sc[l]);
  }
  float p[5], s = 0.f;
#pragma unroll
  for (int l = 0; l < 5; ++l) {
    p[l] = keep[l] ? __expf(sc[l] - m) : 0.f;
    s += p[l];
  }
  const float inv = 1.f / s;

  float gg[16], bb[16];
  {
    const float* gp = att_g + lane * 16;
    const float* bp = att_b + lane * 16;
#pragma unroll
    for (int q = 0; q < 4; ++q) {
      f32x4 gv = *(const f32x4*)(gp + q * 4);
      f32x4 bv = *(const f32x4*)(bp + q * 4);
#pragma unroll
      for (int c = 0; c < 4; ++c) { gg[q * 4 + c] = gv[c]; bb[q * 4 + c] = bv[c]; }
    }
  }

#pragma unroll
  for (int l = 0; l < 5; ++l) {
    const unsigned short* vp = uv + ubase + l * 2048 + 1024;
    float vv[16];
    unpack8(*(const uint4*)vp, vv); unpack8(*(const uint4*)(vp + 8), vv + 8);
    const float pl = p[l] * inv;
    float t[16], sm = 0.f, sq = 0.f;
#pragma unroll
    for (int c = 0; c < 16; ++c) {
      t[c] = pl * vv[c] + xr[l][c];
      sm += t[c];
      sq += t[c] * t[c];
    }
#pragma unroll
    for (int off = 32; off; off >>= 1) {
      sm += __shfl_xor(sm, off);
      sq += __shfl_xor(sq, off);
    }
    const float mu = sm * (1.f / 1024.f);
    const float var = sq * (1.f / 1024.f) - mu * mu;
    const float rs = rsqrtf(var + 1e-5f);
    unsigned short r[16];
#pragma unroll
    for (int c = 0; c < 16; ++c) r[c] = f2bf((t[c] - mu) * rs * gg[c] + bb[c]);
    uint4 o0, o1;
    o0.x = (unsigned)r[0] | ((unsigned)r[1] << 16);  o0.y = (unsigned)r[2] | ((unsigned)r[3] << 16);
    o0.z = (unsigned)r[4] | ((unsigned)r[5] << 16);  o0.w = (unsigned)r[6] | ((unsigned)r[7] << 16);
    o1.x = (unsigned)r[8] | ((unsigned)r[9] << 16);  o1.y = (unsigned)r[10] | ((unsigned)r[11] << 16);
    o1.z = (unsigned)r[12] | ((unsigned)r[13] << 16); o1.w = (unsigned)r[14] | ((unsigned)r[15] << 16);
    unsigned short* yp = yb + xbase + l * 1024;
    *(uint4*)yp = o0;
    *(uint4*)(yp + 8) = o1;
  }
}

// ---------------- final LN in-place on d_out (fp32) ----------------
__global__ void __launch_bounds__(256) k_ln_final(float* __restrict__ z,
                                                  const float* __restrict__ g,
                                                  const float* __restrict__ bb) {
  const int lane = threadIdx.x & 63;
  const long row = (long)blockIdx.x * 4 + (threadIdx.x >> 6);
  float* p = z + row * DD + lane * 16;
  f32x4 v[4];
  float sm = 0.f, sq = 0.f;
#pragma unroll
  for (int q = 0; q < 4; ++q) {
    v[q] = *(const f32x4*)(p + q * 4);
#pragma unroll
    for (int c = 0; c < 4; ++c) { sm += v[q][c]; sq += v[q][c] * v[q][c]; }
  }
#pragma unroll
  for (int off = 32; off; off >>= 1) {
    sm += __shfl_xor(sm, off);
    sq += __shfl_xor(sq, off);
  }
  const float mu = sm * (1.f / 1024.f);
  const float var = sq * (1.f / 1024.f) - mu * mu;
  const float rs = rsqrtf(var + 1e-5f);
  const float* gp = g + lane * 16;
  const float* bp = bb + lane * 16;
#pragma unroll
  for (int q = 0; q < 4; ++q) {
    f32x4 gv = *(const f32x4*)(gp + q * 4);
    f32x4 bv = *(const f32x4*)(bp + q * 4);
#pragma unroll
    for (int c = 0; c < 4; ++c) v[q][c] = (v[q][c] - mu) * rs * gv[c] + bv[c];
    *(f32x4*)(p + q * 4) = v[q];
  }
}

extern "C" void kernel_launch(void* const* d_in, const int* in_sizes, int n_in,
                              void* d_out, int out_size, void* d_ws, size_t ws_size,
                              hipStream_t stream) {
  const float* x     = (const float*)d_in[0];
  const int*   mask  = (const int*)d_in[1];
  const float* Wq    = (const float*)d_in[2];
  const float* Wk    = (const float*)d_in[3];
  const float* Wv    = (const float*)d_in[4];
  const float* W1    = (const float*)d_in[5];
  const float* b1    = (const float*)d_in[6];
  const float* W2    = (const float*)d_in[7];
  const float* b2    = (const float*)d_in[8];
  const float* att_g = (const float*)d_in[9];
  const float* att_b = (const float*)d_in[10];
  const float* ff_g  = (const float*)d_in[11];
  const float* ff_b  = (const float*)d_in[12];

  const long NE = NROWS * DD;
  unsigned short* xb   = (unsigned short*)d_ws;      // bf16 x, becomes y in place
  unsigned short* hb   = xb + NE;                    // GELU output
  unsigned short* Bcat = hb + NE;                    // [Gt ; Wv]  (2048 x 1024)
  unsigned short* W1b  = Bcat + 2L * DD * DD;
  unsigned short* W2b  = W1b + (long)DD * DD;

  unsigned short* uvb = (unsigned short*)d_out;      // [M][2048] bf16, exact fit
  float* outf = (float*)d_out;

  k_cvt_bf16<<<2048, 256, 0, stream>>>(x, xb, NE);
  k_cvt_bf16<<<512, 256, 0, stream>>>(Wv, Bcat + (long)DD * DD, (long)DD * DD);
  k_cvt_bf16<<<512, 256, 0, stream>>>(W1, W1b, (long)DD * DD);
  k_cvt_bf16<<<512, 256, 0, stream>>>(W2, W2b, (long)DD * DD);
  k_gt<<<dim3(16, 64), dim3(16, 16), 0, stream>>>(Wq, Wk, Bcat);

  // [u|v] = xb @ Bcat^T : M=81920, N=2048  -> 320*8 blocks
  k_gemm256<0><<<2560, 512, 0, stream>>>(xb, Bcat, uvb, nullptr, nullptr, nullptr, 3, 2048);
  k_attn_ln<<<4096, 256, 0, stream>>>(xb, uvb, xb, mask, att_g, att_b);
  // h = GELU(y @ W1^T + b1) : N=1024 -> 320*4 blocks
  k_gemm256<1><<<1280, 512, 0, stream>>>(xb, W1b, hb, nullptr, b1, nullptr, 2, 1024);
  // z = h @ W2^T + b2 + y -> fp32 d_out
  k_gemm256<2><<<1280, 512, 0, stream>>>(hb, W2b, nullptr, outf, b2, xb, 2, 1024);
  k_ln_final<<<20480, 256, 0, stream>>>(outf, ff_g, ff_b);
}

// Round 3
// 1269.492 us; speedup vs baseline: 1.3671x; 1.0632x over previous
//
#include <hip/hip_runtime.h>
#include <hip/hip_bf16.h>
#include <cstdint>

// B=16384, L=5, D=1024.  M = 81920 rows.
// scores = x^T (Wq^T Wk) x  ->  Gt[n,k]; u = x@Gt^T; s = rowdot(u,x)/32.
// Pipeline:
//   k_cvt_bf16: x->xb ; Wv->Bcat[1024:2048] ; W1->W1b ; W2->W2b
//   k_gt:       Gt -> Bcat[0:1024]
//   k_gemm256<0>: [u|v] = xb @ Bcat^T  -> d_out as bf16 [M][2048]
//   k_attn_ln:  scores->softmax->attn, y = LN(attn+x) -> xb in place
//   k_gemm256<1>: h = GELU(y @ W1^T + b1) -> hb
//   k_gemm256<3|2>: z = h @ W2^T + b2 + y -> zb bf16 (ws) | d_out fp32
//   k_ln_final*: LN(z)*ff_g+ff_b -> d_out fp32
//
// GEMM: 256x256 tile, BK=32, ring-4 LDS slots (128 KiB), 2-phase interleaved
// K-tile (T3+T4): per phase {ds_read frag subtile; stage half-tile; barrier;
// lgkmcnt(0); setprio(1); 16 MFMA; setprio(0)}, one counted vmcnt(8)/K-tile.
// XOR-swizzled LDS (pre-swizzled global src), bijective XCD chunking.

typedef float f32x4 __attribute__((ext_vector_type(4)));
typedef __bf16 bf16x8 __attribute__((ext_vector_type(8)));

#define DD 1024
#define NROWS 81920L

__device__ __forceinline__ unsigned short f2bf(float f) {
  union { float f; unsigned u; } c; c.f = f;
  unsigned u = c.u;
  return (unsigned short)((u + 0x7FFFu + ((u >> 16) & 1u)) >> 16);  // RNE
}
__device__ __forceinline__ float bf2f(unsigned short b) {
  union { unsigned u; float f; } c; c.u = ((unsigned)b) << 16;
  return c.f;
}
__device__ __forceinline__ void unpack8(uint4 v, float* o) {
  o[0] = bf2f((unsigned short)(v.x & 0xffffu)); o[1] = bf2f((unsigned short)(v.x >> 16));
  o[2] = bf2f((unsigned short)(v.y & 0xffffu)); o[3] = bf2f((unsigned short)(v.y >> 16));
  o[4] = bf2f((unsigned short)(v.z & 0xffffu)); o[5] = bf2f((unsigned short)(v.z >> 16));
  o[6] = bf2f((unsigned short)(v.w & 0xffffu)); o[7] = bf2f((unsigned short)(v.w >> 16));
}
__device__ __forceinline__ void gload_lds16(const void* g, void* l) {
  __builtin_amdgcn_global_load_lds(
      (const __attribute__((address_space(1))) unsigned int*)g,
      (__attribute__((address_space(3))) unsigned int*)l, 16, 0, 0);
}

// ---------------- fp32 -> bf16 ----------------
__global__ void __launch_bounds__(256) k_cvt_bf16(const float* __restrict__ in,
                                                  unsigned short* __restrict__ out, long n) {
  long i = ((long)blockIdx.x * blockDim.x + threadIdx.x) * 8;
  long stride = (long)gridDim.x * blockDim.x * 8;
  for (; i < n; i += stride) {
    f32x4 a = *(const f32x4*)(in + i);
    f32x4 b = *(const f32x4*)(in + i + 4);
    uint4 o;
    o.x = (unsigned)f2bf(a[0]) | ((unsigned)f2bf(a[1]) << 16);
    o.y = (unsigned)f2bf(a[2]) | ((unsigned)f2bf(a[3]) << 16);
    o.z = (unsigned)f2bf(b[0]) | ((unsigned)f2bf(b[1]) << 16);
    o.w = (unsigned)f2bf(b[2]) | ((unsigned)f2bf(b[3]) << 16);
    *(uint4*)(out + i) = o;
  }
}

// ---------------- Gt[n,k] = sum_e Wk[e,n] * Wq[e,k] ----------------
__global__ void __launch_bounds__(256) k_gt(const float* __restrict__ Wq,
                                            const float* __restrict__ Wk,
                                            unsigned short* __restrict__ Gt) {
  __shared__ float sk[16][16];
  __shared__ float sq[16][64];
  const int tx = threadIdx.x, ty = threadIdx.y;
  const int n0 = blockIdx.y * 16;
  const int k0 = blockIdx.x * 64;
  float acc[4] = {0.f, 0.f, 0.f, 0.f};
  for (int e0 = 0; e0 < 1024; e0 += 16) {
    sk[ty][tx] = Wk[(long)(e0 + ty) * DD + n0 + tx];
    *(f32x4*)&sq[ty][tx * 4] = *(const f32x4*)&Wq[(long)(e0 + ty) * DD + k0 + tx * 4];
    __syncthreads();
#pragma unroll
    for (int ee = 0; ee < 16; ++ee) {
      float kv = sk[ee][ty];
      f32x4 qv = *(const f32x4*)&sq[ee][tx * 4];
      acc[0] += kv * qv[0]; acc[1] += kv * qv[1];
      acc[2] += kv * qv[2]; acc[3] += kv * qv[3];
    }
    __syncthreads();
  }
  uint2 o;
  o.x = (unsigned)f2bf(acc[0]) | ((unsigned)f2bf(acc[1]) << 16);
  o.y = (unsigned)f2bf(acc[2]) | ((unsigned)f2bf(acc[3]) << 16);
  *(uint2*)&Gt[(long)(n0 + ty) * DD + k0 + tx * 4] = o;
}

// ---------------- 256x256 BT-GEMM, BK=32, ring-4, 2-phase interleave ----------------
// EPI 0: bf16 out.  EPI 1: GELU(acc+bias) bf16.  EPI 2: acc+bias+resid -> fp32.
// EPI 3: acc+bias+resid -> bf16.
#define VMBAR(N)                                             \
  do {                                                       \
    asm volatile("s_waitcnt vmcnt(" #N ")" ::: "memory");    \
    __builtin_amdgcn_s_barrier();                            \
    asm volatile("" ::: "memory");                           \
  } while (0)

template <int EPI>
__global__ void __launch_bounds__(512, 2) k_gemm256(
    const unsigned short* __restrict__ A,   // [M,1024] bf16
    const unsigned short* __restrict__ B,   // [N,1024] bf16 (BT layout)
    unsigned short* __restrict__ outb,
    float* __restrict__ outf,
    const float* __restrict__ bias,
    const unsigned short* __restrict__ resid,
    const int ntl2,                          // log2(n-tiles)
    const int cst) {                         // C col-stride (elems)
  __shared__ __align__(16) char ldsB[131072];  // 4 slots x (A 16K + B 16K)
  const int tid = threadIdx.x;
  const int lane = tid & 63;
  const int wid = tid >> 6;
  const int wm = wid >> 2, wn = wid & 3;

  // bijective XCD chunking; m-major so n-blocks sharing an A-strip co-reside
  const int nwg = gridDim.x;
  const int cpx = nwg >> 3;
  const int d = blockIdx.x;
  const int l = (d & 7) * cpx + (d >> 3);
  const int mt = l >> ntl2;
  const int nt = l & ((1 << ntl2) - 1);
  const long m0 = (long)mt * 256;
  const int n0 = nt * 256;

  // ---- staging addressing (linear LDS dest, pre-swizzled global source) ----
  // slot region: [256 rows][64 B]; swizzle: byte ^= ((row>>1)&3)<<4
  const int r0off = tid * 16;
  const int r1off = 8192 + tid * 16;
  const int rw0 = r0off >> 6, rw1 = r1off >> 6;
  const int oc0 = (r0off & 63) ^ (((rw0 >> 1) & 3) << 4);
  const int oc1 = (r1off & 63) ^ (((rw1 >> 1) & 3) << 4);
  const char* sA0 = (const char*)A + (m0 + rw0) * 2048 + oc0;
  const char* sA1 = (const char*)A + (m0 + rw1) * 2048 + oc1;
  const char* sB0 = (const char*)B + (long)(n0 + rw0) * 2048 + oc0;
  const char* sB1 = (const char*)B + (long)(n0 + rw1) * 2048 + oc1;

  // ---- fragment read offsets (swizzled) ----
  const int la = lane & 15, lg = lane >> 4;
  const int cb = ((lg ^ ((la >> 1) & 3)) << 4);
  int aoff[8], boff[4];
#pragma unroll
  for (int mi = 0; mi < 8; ++mi) aoff[mi] = (wm * 128 + mi * 16 + la) * 64 + cb;
#pragma unroll
  for (int nj = 0; nj < 4; ++nj) boff[nj] = (wn * 64 + nj * 16 + la) * 64 + cb;

  f32x4 acc[8][4];
#pragma unroll
  for (int mi = 0; mi < 8; ++mi)
#pragma unroll
    for (int nj = 0; nj < 4; ++nj) acc[mi][nj] = f32x4{0.f, 0.f, 0.f, 0.f};

  auto stageA = [&](int kt) {
    char* base = ldsB + ((kt & 3) << 15);
    const long ko = (long)kt << 6;
    gload_lds16(sA0 + ko, base + r0off);
    gload_lds16(sA1 + ko, base + r1off);
  };
  auto stageB = [&](int kt) {
    char* base = ldsB + ((kt & 3) << 15) + 16384;
    const long ko = (long)kt << 6;
    gload_lds16(sB0 + ko, base + r0off);
    gload_lds16(sB1 + ko, base + r1off);
  };

  auto tile = [&](int kt, bool st) {
    const char* bA = ldsB + ((kt & 3) << 15);
    const char* bB = bA + 16384;
    bf16x8 fa[4], fb[4];
    // ---- phase 0: A frags 0-3 + all B frags; MFMA quadrant rows 0-3 ----
#pragma unroll
    for (int i = 0; i < 4; ++i) fa[i] = *(const bf16x8*)(bA + aoff[i]);
#pragma unroll
    for (int j = 0; j < 4; ++j) fb[j] = *(const bf16x8*)(bB + boff[j]);
    if (st) stageA(kt + 3);
    __builtin_amdgcn_s_barrier();
    asm volatile("s_waitcnt lgkmcnt(0)" ::: "memory");
    __builtin_amdgcn_sched_barrier(0);
    __builtin_amdgcn_s_setprio(1);
#pragma unroll
    for (int i = 0; i < 4; ++i)
#pragma unroll
      for (int j = 0; j < 4; ++j)
        acc[i][j] = __builtin_amdgcn_mfma_f32_16x16x32_bf16(fa[i], fb[j], acc[i][j], 0, 0, 0);
    __builtin_amdgcn_s_setprio(0);
    __builtin_amdgcn_s_barrier();
    // ---- phase 1: A frags 4-7 (B reused from regs); MFMA rows 4-7 ----
#pragma unroll
    for (int i = 0; i < 4; ++i) fa[i] = *(const bf16x8*)(bA + aoff[4 + i]);
    if (st) stageB(kt + 3);
    __builtin_amdgcn_s_barrier();
    asm volatile("s_waitcnt lgkmcnt(0)" ::: "memory");
    __builtin_amdgcn_sched_barrier(0);
    __builtin_amdgcn_s_setprio(1);
#pragma unroll
    for (int i = 0; i < 4; ++i)
#pragma unroll
      for (int j = 0; j < 4; ++j)
        acc[4 + i][j] = __builtin_amdgcn_mfma_f32_16x16x32_bf16(fa[i], fb[j], acc[4 + i][j], 0, 0, 0);
    __builtin_amdgcn_s_setprio(0);
  };

  // prologue: tiles 0,1,2 staged; first tile (4 loads) must land -> vmcnt(8)
  stageA(0); stageB(0); stageA(1); stageB(1); stageA(2); stageB(2);
  VMBAR(8);

  for (int kt = 0; kt < 29; ++kt) {
    tile(kt, true);
    VMBAR(8);
  }
  tile(29, false); VMBAR(4);
  tile(30, false); VMBAR(0);
  tile(31, false);

  // ---- epilogue ----
  const long rbase = m0 + wm * 128 + (lane >> 4) * 4;
  const int cbase = n0 + wn * 64 + la;
#pragma unroll
  for (int mi = 0; mi < 8; ++mi) {
#pragma unroll
    for (int nj = 0; nj < 4; ++nj) {
      const int col = cbase + nj * 16;
      float bv = 0.f;
      if constexpr (EPI != 0) bv = bias[col];
#pragma unroll
      for (int t = 0; t < 4; ++t) {
        const long r = rbase + mi * 16 + t;
        float v = acc[mi][nj][t];
        if constexpr (EPI == 0) {
          outb[r * (long)cst + col] = f2bf(v);
        } else if constexpr (EPI == 1) {
          v += bv;
          v = 0.5f * v * (1.0f + erff(v * 0.70710678118654752f));
          outb[r * (long)cst + col] = f2bf(v);
        } else if constexpr (EPI == 2) {
          v += bv + bf2f(resid[r * (long)cst + col]);
          outf[r * (long)cst + col] = v;
        } else {
          v += bv + bf2f(resid[r * (long)cst + col]);
          outb[r * (long)cst + col] = f2bf(v);
        }
      }
    }
  }
}

// ---------------- attn + LN (uv interleaved [M][2048]) ----------------
__global__ void __launch_bounds__(256) k_attn_ln(
    const unsigned short* __restrict__ xb, const unsigned short* __restrict__ uv,
    unsigned short* __restrict__ yb, const int* __restrict__ mask,
    const float* __restrict__ att_g, const float* __restrict__ att_b) {
  const int b = blockIdx.x * 4 + (threadIdx.x >> 6);
  const int lane = threadIdx.x & 63;
  const long xbase = (long)b * 5120 + lane * 16;
  const long ubase = (long)b * 10240 + lane * 16;

  float xr[5][16];
  float sc[5];
#pragma unroll
  for (int l = 0; l < 5; ++l) {
    const unsigned short* xp = xb + xbase + l * 1024;
    const unsigned short* up = uv + ubase + l * 2048;
    unpack8(*(const uint4*)xp, xr[l]); unpack8(*(const uint4*)(xp + 8), xr[l] + 8);
    float uu[16];
    unpack8(*(const uint4*)up, uu); unpack8(*(const uint4*)(up + 8), uu + 8);
    float d = 0.f;
#pragma unroll
    for (int c = 0; c < 16; ++c) d += xr[l][c] * uu[c];
#pragma unroll
    for (int off = 32; off; off >>= 1) d += __shfl_xor(d, off);
    sc[l] = d * 0.03125f;
  }
  bool keep[5];
  float m = -1e30f;
#pragma unroll
  for (int l = 0; l < 5; ++l) {
    keep[l] = (mask[l] != 0);
    if (keep[l]) m = fmaxf(m, sc[l]);
  }
  float p[5], s = 0.f;
#pragma unroll
  for (int l = 0; l < 5; ++l) {
    p[l] = keep[l] ? __expf(sc[l] - m) : 0.f;
    s += p[l];
  }
  const float inv = 1.f / s;

  float gg[16], bb[16];
  {
    const float* gp = att_g + lane * 16;
    const float* bp = att_b + lane * 16;
#pragma unroll
    for (int q = 0; q < 4; ++q) {
      f32x4 gv = *(const f32x4*)(gp + q * 4);
      f32x4 bv = *(const f32x4*)(bp + q * 4);
#pragma unroll
      for (int c = 0; c < 4; ++c) { gg[q * 4 + c] = gv[c]; bb[q * 4 + c] = bv[c]; }
    }
  }

#pragma unroll
  for (int l = 0; l < 5; ++l) {
    const unsigned short* vp = uv + ubase + l * 2048 + 1024;
    float vv[16];
    unpack8(*(const uint4*)vp, vv); unpack8(*(const uint4*)(vp + 8), vv + 8);
    const float pl = p[l] * inv;
    float t[16], sm = 0.f, sq = 0.f;
#pragma unroll
    for (int c = 0; c < 16; ++c) {
      t[c] = pl * vv[c] + xr[l][c];
      sm += t[c];
      sq += t[c] * t[c];
    }
#pragma unroll
    for (int off = 32; off; off >>= 1) {
      sm += __shfl_xor(sm, off);
      sq += __shfl_xor(sq, off);
    }
    const float mu = sm * (1.f / 1024.f);
    const float var = sq * (1.f / 1024.f) - mu * mu;
    const float rs = rsqrtf(var + 1e-5f);
    unsigned short r[16];
#pragma unroll
    for (int c = 0; c < 16; ++c) r[c] = f2bf((t[c] - mu) * rs * gg[c] + bb[c]);
    uint4 o0, o1;
    o0.x = (unsigned)r[0] | ((unsigned)r[1] << 16);  o0.y = (unsigned)r[2] | ((unsigned)r[3] << 16);
    o0.z = (unsigned)r[4] | ((unsigned)r[5] << 16);  o0.w = (unsigned)r[6] | ((unsigned)r[7] << 16);
    o1.x = (unsigned)r[8] | ((unsigned)r[9] << 16);  o1.y = (unsigned)r[10] | ((unsigned)r[11] << 16);
    o1.z = (unsigned)r[12] | ((unsigned)r[13] << 16); o1.w = (unsigned)r[14] | ((unsigned)r[15] << 16);
    unsigned short* yp = yb + xbase + l * 1024;
    *(uint4*)yp = o0;
    *(uint4*)(yp + 8) = o1;
  }
}

// ---------------- final LN, fp32 z in-place ----------------
__global__ void __launch_bounds__(256) k_ln_final(float* __restrict__ z,
                                                  const float* __restrict__ g,
                                                  const float* __restrict__ bb) {
  const int lane = threadIdx.x & 63;
  const long row = (long)blockIdx.x * 4 + (threadIdx.x >> 6);
  float* p = z + row * DD + lane * 16;
  f32x4 v[4];
  float sm = 0.f, sq = 0.f;
#pragma unroll
  for (int q = 0; q < 4; ++q) {
    v[q] = *(const f32x4*)(p + q * 4);
#pragma unroll
    for (int c = 0; c < 4; ++c) { sm += v[q][c]; sq += v[q][c] * v[q][c]; }
  }
#pragma unroll
  for (int off = 32; off; off >>= 1) {
    sm += __shfl_xor(sm, off);
    sq += __shfl_xor(sq, off);
  }
  const float mu = sm * (1.f / 1024.f);
  const float var = sq * (1.f / 1024.f) - mu * mu;
  const float rs = rsqrtf(var + 1e-5f);
  const float* gp = g + lane * 16;
  const float* bp = bb + lane * 16;
#pragma unroll
  for (int q = 0; q < 4; ++q) {
    f32x4 gv = *(const f32x4*)(gp + q * 4);
    f32x4 bv = *(const f32x4*)(bp + q * 4);
#pragma unroll
    for (int c = 0; c < 4; ++c) v[q][c] = (v[q][c] - mu) * rs * gv[c] + bv[c];
    *(f32x4*)(p + q * 4) = v[q];
  }
}

// ---------------- final LN, bf16 z -> fp32 out ----------------
__global__ void __launch_bounds__(256) k_ln_final_bf(const unsigned short* __restrict__ zb,
                                                     float* __restrict__ out,
                                                     const float* __restrict__ g,
                                                     const float* __restrict__ bb) {
  const int lane = threadIdx.x & 63;
  const long row = (long)blockIdx.x * 4 + (threadIdx.x >> 6);
  const unsigned short* p = zb + row * DD + lane * 16;
  float t[16];
  unpack8(*(const uint4*)p, t);
  unpack8(*(const uint4*)(p + 8), t + 8);
  float sm = 0.f, sq = 0.f;
#pragma unroll
  for (int c = 0; c < 16; ++c) { sm += t[c]; sq += t[c] * t[c]; }
#pragma unroll
  for (int off = 32; off; off >>= 1) {
    sm += __shfl_xor(sm, off);
    sq += __shfl_xor(sq, off);
  }
  const float mu = sm * (1.f / 1024.f);
  const float var = sq * (1.f / 1024.f) - mu * mu;
  const float rs = rsqrtf(var + 1e-5f);
  float* op = out + row * DD + lane * 16;
  const float* gp = g + lane * 16;
  const float* bp = bb + lane * 16;
#pragma unroll
  for (int q = 0; q < 4; ++q) {
    f32x4 gv = *(const f32x4*)(gp + q * 4);
    f32x4 bv = *(const f32x4*)(bp + q * 4);
    f32x4 o;
#pragma unroll
    for (int c = 0; c < 4; ++c) o[c] = (t[q * 4 + c] - mu) * rs * gv[c] + bv[c];
    *(f32x4*)(op + q * 4) = o;
  }
}

extern "C" void kernel_launch(void* const* d_in, const int* in_sizes, int n_in,
                              void* d_out, int out_size, void* d_ws, size_t ws_size,
                              hipStream_t stream) {
  const float* x     = (const float*)d_in[0];
  const int*   mask  = (const int*)d_in[1];
  const float* Wq    = (const float*)d_in[2];
  const float* Wk    = (const float*)d_in[3];
  const float* Wv    = (const float*)d_in[4];
  const float* W1    = (const float*)d_in[5];
  const float* b1    = (const float*)d_in[6];
  const float* W2    = (const float*)d_in[7];
  const float* b2    = (const float*)d_in[8];
  const float* att_g = (const float*)d_in[9];
  const float* att_b = (const float*)d_in[10];
  const float* ff_g  = (const float*)d_in[11];
  const float* ff_b  = (const float*)d_in[12];

  const long NE = NROWS * DD;
  unsigned short* xb   = (unsigned short*)d_ws;      // bf16 x, becomes y in place
  unsigned short* hb   = xb + NE;                    // GELU output
  unsigned short* Bcat = hb + NE;                    // [Gt ; Wv]  (2048 x 1024)
  unsigned short* W1b  = Bcat + 2L * DD * DD;
  unsigned short* W2b  = W1b + (long)DD * DD;
  unsigned short* zb   = W2b + (long)DD * DD;        // bf16 z (optional)

  const size_t need_zb = (size_t)(3L * NE + 4L * DD * DD) * 2;
  const bool use_zb = ws_size >= need_zb;

  unsigned short* uvb = (unsigned short*)d_out;      // [M][2048] bf16, exact fit
  float* outf = (float*)d_out;

  k_cvt_bf16<<<2048, 256, 0, stream>>>(x, xb, NE);
  k_cvt_bf16<<<512, 256, 0, stream>>>(Wv, Bcat + (long)DD * DD, (long)DD * DD);
  k_cvt_bf16<<<512, 256, 0, stream>>>(W1, W1b, (long)DD * DD);
  k_cvt_bf16<<<512, 256, 0, stream>>>(W2, W2b, (long)DD * DD);
  k_gt<<<dim3(16, 64), dim3(16, 16), 0, stream>>>(Wq, Wk, Bcat);

  // [u|v] = xb @ Bcat^T : M=81920, N=2048  -> 320*8 blocks
  k_gemm256<0><<<2560, 512, 0, stream>>>(xb, Bcat, uvb, nullptr, nullptr, nullptr, 3, 2048);
  k_attn_ln<<<4096, 256, 0, stream>>>(xb, uvb, xb, mask, att_g, att_b);
  // h = GELU(y @ W1^T + b1) : N=1024 -> 320*4 blocks
  k_gemm256<1><<<1280, 512, 0, stream>>>(xb, W1b, hb, nullptr, b1, nullptr, 2, 1024);
  if (use_zb) {
    // z = h @ W2^T + b2 + y -> bf16 zb, then LN -> fp32 d_out
    k_gemm256<3><<<1280, 512, 0, stream>>>(hb, W2b, zb, nullptr, b2, xb, 2, 1024);
    k_ln_final_bf<<<20480, 256, 0, stream>>>(zb, outf, ff_g, ff_b);
  } else {
    k_gemm256<2><<<1280, 512, 0, stream>>>(hb, W2b, nullptr, outf, b2, xb, 2, 1024);
    k_ln_final<<<20480, 256, 0, stream>>>(outf, ff_g, ff_b);
  }
}